// Round 12
// baseline (118.330 us; speedup 1.0000x reference)
//
#include <hip/hip_runtime.h>
#include <hip/hip_bf16.h>
#include <math.h>

// ---------------- problem constants ----------------
#define S        2048
#define HIDDEN   1024
#define NH       16
#define NKV      4
#define HD       64
#define NQKV     1536         // 1024 q + 256 k + 256 v
#define VW       2128         // vTs row width: 64 halo + 2048 + 16 tail

typedef _Float16 f16x8 __attribute__((ext_vector_type(8)));
typedef _Float16 f16x4 __attribute__((ext_vector_type(4)));
typedef float    f32x4 __attribute__((ext_vector_type(4)));

// async 16B global->LDS (DMA). LDS dest = wave-uniform base + lane*16.
__device__ __forceinline__ void glds16(const void* g, void* l) {
    __builtin_amdgcn_global_load_lds((const __attribute__((address_space(1))) void*)g,
                                     (__attribute__((address_space(3))) void*)l, 16, 0, 0);
}

// rope column permutation within a 64-col head: blocks reordered
// (0-15, 32-47, 16-31, 48-63) so pair (f, f+32) sits in adjacent 16-col blocks.
// QK dot products are invariant under a common q/k permutation.
__device__ __host__ __forceinline__ int ropePerm(int d) {
    int t = d & 48;
    return (t == 16 || t == 32) ? (d ^ 48) : d;
}

// ---------------- prep: transposes (q/k permuted) + hs convert + rope table + v halo ----
__global__ __launch_bounds__(256) void prep_kernel(const float* __restrict__ hs, _Float16* __restrict__ hsf16,
                                                   const float* __restrict__ wq, const float* __restrict__ wk,
                                                   const float* __restrict__ wvv, const float* __restrict__ wo,
                                                   _Float16* __restrict__ wqkvT, _Float16* __restrict__ woT,
                                                   const int* __restrict__ pos_ids, float2* __restrict__ rope_tab,
                                                   _Float16* __restrict__ vTs) {
    int bid = blockIdx.x;
    int tid = threadIdx.x;
    if (bid >= 4864) {                       // v-halo zero: 256 blocks (one per d row)
        int d = bid - 4864;
        if (tid < 64) vTs[(size_t)d * VW + tid] = (_Float16)0.0f;
        return;
    }
    if (bid >= 4608) {                       // rope table: 2048 x 32 (sin, cos)
        int idx = (bid - 4608) * 256 + tid;
        int s = idx >> 5, f = idx & 31;
        double inv = pow(10000.0, -(double)(2 * f) / 64.0);
        float ang = (float)((double)pos_ids[s] * inv);
        float sn, cs;
        sincosf(ang, &sn, &cs);
        rope_tab[idx] = make_float2(sn, cs);
        return;
    }
    if (bid >= 2560) {                       // hs f32->f16 convert
        int i = (bid - 2560) * 256 + tid;
        float4 v = ((const float4*)hs)[i];
        f16x4 o = { (_Float16)v.x, (_Float16)v.y, (_Float16)v.z, (_Float16)v.w };
        *(f16x4*)(hsf16 + 4 * (size_t)i) = o;
        return;
    }
    // weight transpose: src [1024][Cn] f32 -> dst [Cn][1024] f16 (q/k rows rope-permuted)
    const float* src; _Float16* dst; int Cn, b; bool prm;
    if (bid < 1024)      { src = wq;  dst = wqkvT;                       Cn = 1024; b = bid;        prm = true;  }
    else if (bid < 1280) { src = wk;  dst = wqkvT + (size_t)1024 * 1024; Cn = 256;  b = bid - 1024; prm = true;  }
    else if (bid < 1536) { src = wvv; dst = wqkvT + (size_t)1280 * 1024; Cn = 256;  b = bid - 1280; prm = false; }
    else                 { src = wo;  dst = woT;                         Cn = 1024; b = bid - 1536; prm = false; }
    int xb = Cn >> 5;
    int c0 = (b % xb) * 32;
    int r0 = (b / xb) * 32;
    __shared__ float t[32][33];
    int tx = tid & 31, ty = tid >> 5;
#pragma unroll
    for (int i = ty; i < 32; i += 8)
        t[i][tx] = src[(size_t)(r0 + i) * Cn + c0 + tx];
    __syncthreads();
#pragma unroll
    for (int i = ty; i < 32; i += 8) {
        int n = c0 + i;
        int np = prm ? ((n & ~63) | ropePerm(n & 63)) : n;
        dst[(size_t)np * 1024 + r0 + tx] = (_Float16)t[tx][i];
    }
}

// ---- shared GEMM K-loop: 64x64 tile, 4 waves (2x2, wave tile 32x32), BK=64,
// glds16 DOUBLE-buffer with 4-wave blocks (R10's dbuf retried at full occupancy:
// 3 blocks/CU x 4 waves = 12 waves/CU, LDS 32 KB — identical residency to R11).
// ONE barrier per iter (16 total, same as R11's BK=128) but each barrier's
// vmcnt(0) drain now waits on DMAs issued a full compute phase earlier.
// Trace: prologue stages buf0; iter i: barrier (drains buf p) -> issue DMA for
// p^1 -> compute p. WAR-safe: p^1 reads completed before this iter's barrier.
// XOR chunk swizzle cc^(r&7) keeps frag reads conflict-free on lane-linear LDS.
#define GEMM_STAGE(Aptr, Bptr, k0, buf)                                                         \
    _Pragma("unroll")                                                                           \
    for (int u = 0; u < 2; ++u) {                                                               \
        int r = wv * 16 + u * 8 + dr;                                                           \
        glds16(Aptr + (size_t)(m0 + r) * 1024 + (k0) + ((cc ^ (r & 7)) * 8),                    \
               &As[buf][(wv * 16 + u * 8) * 64]);                                               \
        glds16(Bptr + (size_t)(n0 + r) * 1024 + (k0) + ((cc ^ (r & 7)) * 8),                    \
               &Bs[buf][(wv * 16 + u * 8) * 64]);                                               \
    }

#define GEMM_BODY(Aptr, Bptr)                                                                   \
    f32x4 acc[2][2] = {};                                                                       \
    GEMM_STAGE(Aptr, Bptr, 0, 0)                                                                \
    int p = 0;                                                                                  \
    for (int it = 0; it < 16; ++it) {                                                           \
        __syncthreads();                                                                        \
        if (it < 15) { GEMM_STAGE(Aptr, Bptr, (it + 1) * 64, p ^ 1) }                           \
        _Pragma("unroll")                                                                       \
        for (int ks = 0; ks < 2; ++ks) {                                                        \
            f16x8 a[2], b[2];                                                                   \
            _Pragma("unroll")                                                                   \
            for (int i = 0; i < 2; ++i) {                                                       \
                int row = wm + i * 16 + lr;                                                     \
                a[i] = *(const f16x8*)&As[p][row * 64 + (((ks * 4 + quad) ^ (row & 7)) * 8)];   \
            }                                                                                   \
            _Pragma("unroll")                                                                   \
            for (int j = 0; j < 2; ++j) {                                                       \
                int row = wn + j * 16 + lr;                                                     \
                b[j] = *(const f16x8*)&Bs[p][row * 64 + (((ks * 4 + quad) ^ (row & 7)) * 8)];   \
            }                                                                                   \
            _Pragma("unroll")                                                                   \
            for (int i = 0; i < 2; ++i)                                                         \
                _Pragma("unroll")                                                               \
                for (int j = 0; j < 2; ++j)                                                     \
                    acc[i][j] = __builtin_amdgcn_mfma_f32_16x16x32_f16(a[i], b[j], acc[i][j], 0, 0, 0); \
        }                                                                                       \
        p ^= 1;                                                                                 \
    }

// ---------------- QKV GEMM: 768 tiles (3/CU balanced) + fused rope / v-T epilogue ----------
__global__ __launch_bounds__(256) void gemm_qkv(const _Float16* __restrict__ A,
                                                const _Float16* __restrict__ BT,
                                                _Float16* __restrict__ qkv,
                                                _Float16* __restrict__ vTs,
                                                const float2* __restrict__ rope_tab) {
    __shared__ __align__(16) _Float16 As[2][64 * 64];   // 2 x 8 KB
    __shared__ __align__(16) _Float16 Bs[2][64 * 64];   // 2 x 8 KB
    const int bid  = blockIdx.x;
    const int tid  = threadIdx.x;
    const int lane = tid & 63;
    const int wv   = tid >> 6;
    const int lr   = lane & 15;
    const int quad = lane >> 4;
    const int dr   = lane >> 3;     // staging row-in-8-group
    const int cc   = lane & 7;      // staging 16B chunk
    const int wm   = (wv >> 1) * 32;
    const int wn   = (wv & 1) * 32;
    const int bx = bid % 24, by = bid / 24;
    const int m0 = by * 64, n0 = bx * 64;

    GEMM_BODY(A, BT)

    // epilogue. C/D layout: col=lane&15, row=quad*4+reg  [m89/m91]
    if (n0 < 1280) {
        const bool isq = (n0 < 1024);
        const int  f   = (wn >> 1) + lr;          // rope freq for this 16-col block pair
#pragma unroll
        for (int i = 0; i < 2; ++i)
#pragma unroll
            for (int r = 0; r < 4; ++r) {
                int s = m0 + wm + i * 16 + quad * 4 + r;
                float2 scv = rope_tab[(size_t)s * 32 + f];
                float lo = acc[i][0][r], hi = acc[i][1][r];
                float nlo = lo * scv.y - hi * scv.x;
                float nhi = hi * scv.y + lo * scv.x;
                if (isq) { nlo *= 0.125f; nhi *= 0.125f; }
                qkv[(size_t)s * NQKV + n0 + wn + lr]      = (_Float16)nlo;
                qkv[(size_t)s * NQKV + n0 + wn + 16 + lr] = (_Float16)nhi;
            }
    } else {
#pragma unroll
        for (int i = 0; i < 2; ++i)
#pragma unroll
            for (int j = 0; j < 2; ++j) {
                int d = n0 - 1280 + wn + j * 16 + lr;
                f16x4 h = { (_Float16)acc[i][j][0], (_Float16)acc[i][j][1],
                            (_Float16)acc[i][j][2], (_Float16)acc[i][j][3] };
                *(f16x4*)(vTs + (size_t)d * VW + 64 + m0 + wm + i * 16 + quad * 4) = h;
            }
    }
}

// ---------------- O GEMM: 512 tiles (2/CU balanced), f32 out ----------------
__global__ __launch_bounds__(256) void gemm_o(const _Float16* __restrict__ A,
                                              const _Float16* __restrict__ BT,
                                              float* __restrict__ out) {
    __shared__ __align__(16) _Float16 As[2][64 * 64];
    __shared__ __align__(16) _Float16 Bs[2][64 * 64];
    const int bid  = blockIdx.x;
    const int tid  = threadIdx.x;
    const int lane = tid & 63;
    const int wv   = tid >> 6;
    const int lr   = lane & 15;
    const int quad = lane >> 4;
    const int dr   = lane >> 3;
    const int cc   = lane & 7;
    const int wm   = (wv >> 1) * 32;
    const int wn   = (wv & 1) * 32;
    const int bx = bid % 16, by = bid / 16;
    const int m0 = by * 64, n0 = bx * 64;

    GEMM_BODY(A, BT)

#pragma unroll
    for (int i = 0; i < 2; ++i)
#pragma unroll
        for (int j = 0; j < 2; ++j)
#pragma unroll
            for (int r = 0; r < 4; ++r)
                out[(size_t)(m0 + wm + i * 16 + quad * 4 + r) * 1024 + n0 + wn + j * 16 + lr] = acc[i][j][r];
}

// ---------------- MFMA sliding-window attention (rope pre-applied) ----------------
__global__ __launch_bounds__(256) void attn_mfma(const _Float16* __restrict__ qkv,
                                                 const _Float16* __restrict__ vTs,
                                                 const int* __restrict__ mask,
                                                 _Float16* __restrict__ attn_out) {
    const int s0   = blockIdx.x * 16;
    const int g    = blockIdx.y;
    const int tid  = threadIdx.x;
    const int lane = tid & 63;
    const int wv   = tid >> 6;
    const int h    = g * 4 + wv;
    const int lr   = lane & 15;
    const int quad = lane >> 4;

    __shared__ __align__(16) _Float16 K_lds[80 * 72];
    __shared__ __align__(16) _Float16 Vt_lds[64 * 104];
    __shared__ __align__(16) _Float16 P_lds[4][16 * 104];
    __shared__ int M_lds[1024];

    ((int4*)M_lds)[tid] = ((const int4*)(mask + s0 * 64))[tid];

    // K band rows 0..79, key j = s0-64+r (zero j<0; r=0 masked anyway)
    for (int c = tid; c < 640; c += 256) {
        int r = c >> 3, cl = c & 7;
        int j = s0 - 64 + r;
        f16x8 val = {};
        if (j >= 0)
            val = *(const f16x8*)(qkv + (size_t)j * NQKV + 1024 + g * 64 + cl * 8);
        *(f16x8*)&K_lds[r * 72 + cl * 8] = val;
    }
    // V band from pre-transposed vTs (front halo zero; tail*P=0)
    for (int c = tid; c < 64 * 12; c += 256) {
        int d = c / 12, ch = c % 12;
        *(f16x8*)&Vt_lds[d * 104 + ch * 8] =
            *(const f16x8*)(vTs + (size_t)(g * 64 + d) * VW + s0 + ch * 8);
    }
    f16x8 qf[2];
#pragma unroll
    for (int ks = 0; ks < 2; ++ks)
        qf[ks] = *(const f16x8*)(qkv + (size_t)(s0 + lr) * NQKV + h * 64 + ks * 32 + quad * 8);
    __syncthreads();

    f32x4 sc[5];
#pragma unroll
    for (int t = 0; t < 5; ++t) {
        f32x4 a = {};
#pragma unroll
        for (int ks = 0; ks < 2; ++ks) {
            f16x8 kf = *(const f16x8*)&K_lds[(t * 16 + lr) * 72 + ks * 32 + quad * 8];
            a = __builtin_amdgcn_mfma_f32_16x16x32_f16(qf[ks], kf, a, 0, 0, 0);
        }
        sc[t] = a;
    }
#pragma unroll
    for (int t = 0; t < 5; ++t)
#pragma unroll
        for (int r = 0; r < 4; ++r) {
            int qi = quad * 4 + r;
            int w  = t * 16 + lr - 1 - qi;
            bool ok = (w >= 0) && (w < 64) && (M_lds[qi * 64 + (w & 63)] > 0);
            sc[t][r] = ok ? sc[t][r] : -1e30f;
        }
    float pr[5][4];
#pragma unroll
    for (int r = 0; r < 4; ++r) {
        float mx = -1e30f;
#pragma unroll
        for (int t = 0; t < 5; ++t) mx = fmaxf(mx, sc[t][r]);
#pragma unroll
        for (int off = 1; off < 16; off <<= 1) mx = fmaxf(mx, __shfl_xor(mx, off));
        float sum = 0.f;
#pragma unroll
        for (int t = 0; t < 5; ++t) { float e = __expf(sc[t][r] - mx); pr[t][r] = e; sum += e; }
#pragma unroll
        for (int off = 1; off < 16; off <<= 1) sum += __shfl_xor(sum, off);
        float rs = 1.0f / sum;
#pragma unroll
        for (int t = 0; t < 5; ++t) pr[t][r] *= rs;
    }
    _Float16* myP = P_lds[wv];
    {
        f16x4 z = {};
        *(f16x4*)&myP[lr * 104 + 80 + quad * 4] = z;
    }
#pragma unroll
    for (int t = 0; t < 5; ++t)
#pragma unroll
        for (int r = 0; r < 4; ++r)
            myP[(quad * 4 + r) * 104 + t * 16 + lr] = (_Float16)pr[t][r];
    __syncthreads();

    f32x4 oacc[4] = {};
#pragma unroll
    for (int ks = 0; ks < 3; ++ks) {
        f16x8 pf = *(const f16x8*)&myP[lr * 104 + ks * 32 + quad * 8];
#pragma unroll
        for (int t = 0; t < 4; ++t) {
            f16x8 vf = *(const f16x8*)&Vt_lds[(t * 16 + lr) * 104 + ks * 32 + quad * 8];
            oacc[t] = __builtin_amdgcn_mfma_f32_16x16x32_f16(pf, vf, oacc[t], 0, 0, 0);
        }
    }
#pragma unroll
    for (int t = 0; t < 4; ++t)
#pragma unroll
        for (int r = 0; r < 4; ++r)
            attn_out[(size_t)(s0 + quad * 4 + r) * HIDDEN + h * 64 + t * 16 + lr] = (_Float16)oacc[t][r];
}

// ---------------- launch ----------------
extern "C" void kernel_launch(void* const* d_in, const int* in_sizes, int n_in,
                              void* d_out, int out_size, void* d_ws, size_t ws_size,
                              hipStream_t stream) {
    const float* hs      = (const float*)d_in[0];
    const int*   mask    = (const int*)  d_in[1];
    const int*   pos_ids = (const int*)  d_in[2];
    const float* wq      = (const float*)d_in[3];
    const float* wk      = (const float*)d_in[4];
    const float* wvv     = (const float*)d_in[5];
    const float* wo      = (const float*)d_in[6];
    float* out = (float*)d_out;

    char* ws = (char*)d_ws;
    _Float16* wqkvT   = (_Float16*)(ws + 0);                    // 1536x1024 f16 (3 MB)
    _Float16* woT     = (_Float16*)(ws + (3u << 20));           // 1024x1024 f16 (2 MB)
    _Float16* hsf16   = (_Float16*)(ws + (5u << 20));           // 2048x1024 f16 (4 MB)
    _Float16* qkvf16  = (_Float16*)(ws + (9u << 20));           // 2048x1536 f16 (6 MB)
    _Float16* attnf16 = (_Float16*)(ws + (15u << 20));          // 2048x1024 f16 (4 MB)
    _Float16* vTs     = (_Float16*)(ws + (19u << 20));          // 256x2128  f16 (~1.1 MB)
    float2*   ropeTab = (float2*)  (ws + (21u << 20));          // 2048x32 float2 (512 KB)

    // 1. prep: transposes (2560, q/k rope-permuted) + convert (2048) + rope (256) + halo (256)
    prep_kernel<<<5120, 256, 0, stream>>>(hs, hsf16, wq, wk, wvv, wo, wqkvT, woT,
                                          pos_ids, ropeTab, vTs);
    // 2. QKV projection (768 blocks = 3/CU, 4-wave dbuf BK=64) with fused rope / v-transpose
    gemm_qkv<<<768, 256, 0, stream>>>(hsf16, wqkvT, qkvf16, vTs, ropeTab);
    // 3. attention
    attn_mfma<<<dim3(S / 16, NKV), 256, 0, stream>>>(qkvf16, vTs, mask, attnf16);
    // 4. output projection (512 blocks = 2/CU, 4-wave dbuf BK=64) -> f32 out
    gemm_o<<<512, 256, 0, stream>>>(attnf16, woT, out);
}

// Round 13
// 106.206 us; speedup vs baseline: 1.1142x; 1.1142x over previous
//
#include <hip/hip_runtime.h>
#include <hip/hip_bf16.h>
#include <math.h>

// ---------------- problem constants ----------------
#define S        2048
#define HIDDEN   1024
#define NH       16
#define NKV      4
#define HD       64
#define NQKV     1536         // 1024 q + 256 k + 256 v
#define VW       2128         // vTs row width: 64 halo + 2048 + 16 tail

typedef _Float16 f16x8 __attribute__((ext_vector_type(8)));
typedef _Float16 f16x4 __attribute__((ext_vector_type(4)));
typedef float    f32x4 __attribute__((ext_vector_type(4)));

// async 16B global->LDS (DMA). LDS dest = wave-uniform base + lane*16.
__device__ __forceinline__ void glds16(const void* g, void* l) {
    __builtin_amdgcn_global_load_lds((const __attribute__((address_space(1))) void*)g,
                                     (__attribute__((address_space(3))) void*)l, 16, 0, 0);
}

// rope column permutation within a 64-col head: blocks reordered
// (0-15, 32-47, 16-31, 48-63) so pair (f, f+32) sits in adjacent 16-col blocks.
// QK dot products are invariant under a common q/k permutation.
__device__ __host__ __forceinline__ int ropePerm(int d) {
    int t = d & 48;
    return (t == 16 || t == 32) ? (d ^ 48) : d;
}

// ---------------- prep: transposes (q/k permuted) + hs convert + rope table + v halo ----
__global__ __launch_bounds__(256) void prep_kernel(const float* __restrict__ hs, _Float16* __restrict__ hsf16,
                                                   const float* __restrict__ wq, const float* __restrict__ wk,
                                                   const float* __restrict__ wvv, const float* __restrict__ wo,
                                                   _Float16* __restrict__ wqkvT, _Float16* __restrict__ woT,
                                                   const int* __restrict__ pos_ids, float2* __restrict__ rope_tab,
                                                   _Float16* __restrict__ vTs) {
    int bid = blockIdx.x;
    int tid = threadIdx.x;
    if (bid >= 4864) {                       // v-halo zero: 256 blocks (one per d row)
        int d = bid - 4864;
        if (tid < 64) vTs[(size_t)d * VW + tid] = (_Float16)0.0f;
        return;
    }
    if (bid >= 4608) {                       // rope table: 2048 x 32 (sin, cos)
        int idx = (bid - 4608) * 256 + tid;
        int s = idx >> 5, f = idx & 31;
        double inv = pow(10000.0, -(double)(2 * f) / 64.0);
        float ang = (float)((double)pos_ids[s] * inv);
        float sn, cs;
        sincosf(ang, &sn, &cs);
        rope_tab[idx] = make_float2(sn, cs);
        return;
    }
    if (bid >= 2560) {                       // hs f32->f16 convert
        int i = (bid - 2560) * 256 + tid;
        float4 v = ((const float4*)hs)[i];
        f16x4 o = { (_Float16)v.x, (_Float16)v.y, (_Float16)v.z, (_Float16)v.w };
        *(f16x4*)(hsf16 + 4 * (size_t)i) = o;
        return;
    }
    // weight transpose: src [1024][Cn] f32 -> dst [Cn][1024] f16 (q/k rows rope-permuted)
    const float* src; _Float16* dst; int Cn, b; bool prm;
    if (bid < 1024)      { src = wq;  dst = wqkvT;                       Cn = 1024; b = bid;        prm = true;  }
    else if (bid < 1280) { src = wk;  dst = wqkvT + (size_t)1024 * 1024; Cn = 256;  b = bid - 1024; prm = true;  }
    else if (bid < 1536) { src = wvv; dst = wqkvT + (size_t)1280 * 1024; Cn = 256;  b = bid - 1280; prm = false; }
    else                 { src = wo;  dst = woT;                         Cn = 1024; b = bid - 1536; prm = false; }
    int xb = Cn >> 5;
    int c0 = (b % xb) * 32;
    int r0 = (b / xb) * 32;
    __shared__ float t[32][33];
    int tx = tid & 31, ty = tid >> 5;
#pragma unroll
    for (int i = ty; i < 32; i += 8)
        t[i][tx] = src[(size_t)(r0 + i) * Cn + c0 + tx];
    __syncthreads();
#pragma unroll
    for (int i = ty; i < 32; i += 8) {
        int n = c0 + i;
        int np = prm ? ((n & ~63) | ropePerm(n & 63)) : n;
        dst[(size_t)np * 1024 + r0 + tx] = (_Float16)t[tx][i];
    }
}

// ---- shared GEMM K-loop body: 64x64 tile, 4 waves (2x2, wave tile 32x32), BK=128 ----
// Single-buffer glds16, 2 barriers per iter but only 8 iters (16 drains).
// LDS row = 128 f16 = 16 chunks of 16B; XOR swizzle cc^(r&15): quad lanes read all
// 16 chunks -> 2 lanes per 4-bank group = free 2-way aliasing [m136].
// Staging: each glds16 inst covers 4 rows (dr=lane>>4 row-in-group, cc=lane&15 chunk);
// wave stages 16 rows of A and 16 of B (4+4 insts/iter).
// NOTE (R9-R12 A/B evidence): this plain structure beats BK=64 (R9 111.1),
// 2-wave dbuf (R10 120.0), and 4-wave dbuf (R12 118.3) — do not re-pipeline.
#define GEMM_BODY(Aptr, Bptr)                                                                   \
    f32x4 acc[2][2] = {};                                                                       \
    for (int k0 = 0; k0 < 1024; k0 += 128) {                                                    \
        __syncthreads();                                                                        \
        _Pragma("unroll")                                                                       \
        for (int u = 0; u < 4; ++u) {                                                           \
            int r = wv * 16 + u * 4 + dr;                                                       \
            glds16(Aptr + (size_t)(m0 + r) * 1024 + k0 + ((cc ^ (r & 15)) * 8),                 \
                   As + (wv * 16 + u * 4) * 128);                                               \
            glds16(Bptr + (size_t)(n0 + r) * 1024 + k0 + ((cc ^ (r & 15)) * 8),                 \
                   Bs + (wv * 16 + u * 4) * 128);                                               \
        }                                                                                       \
        __syncthreads();                                                                        \
        _Pragma("unroll")                                                                       \
        for (int ks = 0; ks < 4; ++ks) {                                                        \
            f16x8 a[2], b[2];                                                                   \
            _Pragma("unroll")                                                                   \
            for (int i = 0; i < 2; ++i) {                                                       \
                int row = wm + i * 16 + lr;                                                     \
                a[i] = *(const f16x8*)&As[row * 128 + (((ks * 4 + quad) ^ (row & 15)) * 8)];    \
            }                                                                                   \
            _Pragma("unroll")                                                                   \
            for (int j = 0; j < 2; ++j) {                                                       \
                int row = wn + j * 16 + lr;                                                     \
                b[j] = *(const f16x8*)&Bs[row * 128 + (((ks * 4 + quad) ^ (row & 15)) * 8)];    \
            }                                                                                   \
            _Pragma("unroll")                                                                   \
            for (int i = 0; i < 2; ++i)                                                         \
                _Pragma("unroll")                                                               \
                for (int j = 0; j < 2; ++j)                                                     \
                    acc[i][j] = __builtin_amdgcn_mfma_f32_16x16x32_f16(a[i], b[j], acc[i][j], 0, 0, 0); \
        }                                                                                       \
    }

// ---------------- QKV GEMM: 768 tiles (3/CU balanced) + fused rope / v-T epilogue ----------
__global__ __launch_bounds__(256) void gemm_qkv(const _Float16* __restrict__ A,
                                                const _Float16* __restrict__ BT,
                                                _Float16* __restrict__ qkv,
                                                _Float16* __restrict__ vTs,
                                                const float2* __restrict__ rope_tab) {
    __shared__ __align__(16) _Float16 As[64 * 128];   // 16 KB
    __shared__ __align__(16) _Float16 Bs[64 * 128];   // 16 KB
    const int bid  = blockIdx.x;
    const int tid  = threadIdx.x;
    const int lane = tid & 63;
    const int wv   = tid >> 6;
    const int lr   = lane & 15;
    const int quad = lane >> 4;
    const int dr   = lane >> 4;     // staging row-in-4-group
    const int cc   = lane & 15;     // staging 16B chunk
    const int wm   = (wv >> 1) * 32;
    const int wn   = (wv & 1) * 32;
    const int bx = bid % 24, by = bid / 24;
    const int m0 = by * 64, n0 = bx * 64;

    GEMM_BODY(A, BT)

    // epilogue. C/D layout: col=lane&15, row=quad*4+reg  [m89/m91]
    if (n0 < 1280) {
        const bool isq = (n0 < 1024);
        const int  f   = (wn >> 1) + lr;          // rope freq for this 16-col block pair
#pragma unroll
        for (int i = 0; i < 2; ++i)
#pragma unroll
            for (int r = 0; r < 4; ++r) {
                int s = m0 + wm + i * 16 + quad * 4 + r;
                float2 scv = rope_tab[(size_t)s * 32 + f];
                float lo = acc[i][0][r], hi = acc[i][1][r];
                float nlo = lo * scv.y - hi * scv.x;
                float nhi = hi * scv.y + lo * scv.x;
                if (isq) { nlo *= 0.125f; nhi *= 0.125f; }
                qkv[(size_t)s * NQKV + n0 + wn + lr]      = (_Float16)nlo;
                qkv[(size_t)s * NQKV + n0 + wn + 16 + lr] = (_Float16)nhi;
            }
    } else {
#pragma unroll
        for (int i = 0; i < 2; ++i)
#pragma unroll
            for (int j = 0; j < 2; ++j) {
                int d = n0 - 1280 + wn + j * 16 + lr;
                f16x4 h = { (_Float16)acc[i][j][0], (_Float16)acc[i][j][1],
                            (_Float16)acc[i][j][2], (_Float16)acc[i][j][3] };
                *(f16x4*)(vTs + (size_t)d * VW + 64 + m0 + wm + i * 16 + quad * 4) = h;
            }
    }
}

// ---------------- O GEMM: 512 tiles (2/CU balanced), f32 out ----------------
__global__ __launch_bounds__(256) void gemm_o(const _Float16* __restrict__ A,
                                              const _Float16* __restrict__ BT,
                                              float* __restrict__ out) {
    __shared__ __align__(16) _Float16 As[64 * 128];
    __shared__ __align__(16) _Float16 Bs[64 * 128];
    const int bid  = blockIdx.x;
    const int tid  = threadIdx.x;
    const int lane = tid & 63;
    const int wv   = tid >> 6;
    const int lr   = lane & 15;
    const int quad = lane >> 4;
    const int dr   = lane >> 4;
    const int cc   = lane & 15;
    const int wm   = (wv >> 1) * 32;
    const int wn   = (wv & 1) * 32;
    const int bx = bid % 16, by = bid / 16;
    const int m0 = by * 64, n0 = bx * 64;

    GEMM_BODY(A, BT)

#pragma unroll
    for (int i = 0; i < 2; ++i)
#pragma unroll
        for (int j = 0; j < 2; ++j)
#pragma unroll
            for (int r = 0; r < 4; ++r)
                out[(size_t)(m0 + wm + i * 16 + quad * 4 + r) * 1024 + n0 + wn + j * 16 + lr] = acc[i][j][r];
}

// ---------------- MFMA sliding-window attention (rope pre-applied) ----------------
__global__ __launch_bounds__(256) void attn_mfma(const _Float16* __restrict__ qkv,
                                                 const _Float16* __restrict__ vTs,
                                                 const int* __restrict__ mask,
                                                 _Float16* __restrict__ attn_out) {
    const int s0   = blockIdx.x * 16;
    const int g    = blockIdx.y;
    const int tid  = threadIdx.x;
    const int lane = tid & 63;
    const int wv   = tid >> 6;
    const int h    = g * 4 + wv;
    const int lr   = lane & 15;
    const int quad = lane >> 4;

    __shared__ __align__(16) _Float16 K_lds[80 * 72];
    __shared__ __align__(16) _Float16 Vt_lds[64 * 104];
    __shared__ __align__(16) _Float16 P_lds[4][16 * 104];
    __shared__ int M_lds[1024];

    ((int4*)M_lds)[tid] = ((const int4*)(mask + s0 * 64))[tid];

    // K band rows 0..79, key j = s0-64+r (zero j<0; r=0 masked anyway)
    for (int c = tid; c < 640; c += 256) {
        int r = c >> 3, cl = c & 7;
        int j = s0 - 64 + r;
        f16x8 val = {};
        if (j >= 0)
            val = *(const f16x8*)(qkv + (size_t)j * NQKV + 1024 + g * 64 + cl * 8);
        *(f16x8*)&K_lds[r * 72 + cl * 8] = val;
    }
    // V band from pre-transposed vTs (front halo zero; tail*P=0)
    for (int c = tid; c < 64 * 12; c += 256) {
        int d = c / 12, ch = c % 12;
        *(f16x8*)&Vt_lds[d * 104 + ch * 8] =
            *(const f16x8*)(vTs + (size_t)(g * 64 + d) * VW + s0 + ch * 8);
    }
    f16x8 qf[2];
#pragma unroll
    for (int ks = 0; ks < 2; ++ks)
        qf[ks] = *(const f16x8*)(qkv + (size_t)(s0 + lr) * NQKV + h * 64 + ks * 32 + quad * 8);
    __syncthreads();

    f32x4 sc[5];
#pragma unroll
    for (int t = 0; t < 5; ++t) {
        f32x4 a = {};
#pragma unroll
        for (int ks = 0; ks < 2; ++ks) {
            f16x8 kf = *(const f16x8*)&K_lds[(t * 16 + lr) * 72 + ks * 32 + quad * 8];
            a = __builtin_amdgcn_mfma_f32_16x16x32_f16(qf[ks], kf, a, 0, 0, 0);
        }
        sc[t] = a;
    }
#pragma unroll
    for (int t = 0; t < 5; ++t)
#pragma unroll
        for (int r = 0; r < 4; ++r) {
            int qi = quad * 4 + r;
            int w  = t * 16 + lr - 1 - qi;
            bool ok = (w >= 0) && (w < 64) && (M_lds[qi * 64 + (w & 63)] > 0);
            sc[t][r] = ok ? sc[t][r] : -1e30f;
        }
    float pr[5][4];
#pragma unroll
    for (int r = 0; r < 4; ++r) {
        float mx = -1e30f;
#pragma unroll
        for (int t = 0; t < 5; ++t) mx = fmaxf(mx, sc[t][r]);
#pragma unroll
        for (int off = 1; off < 16; off <<= 1) mx = fmaxf(mx, __shfl_xor(mx, off));
        float sum = 0.f;
#pragma unroll
        for (int t = 0; t < 5; ++t) { float e = __expf(sc[t][r] - mx); pr[t][r] = e; sum += e; }
#pragma unroll
        for (int off = 1; off < 16; off <<= 1) sum += __shfl_xor(sum, off);
        float rs = 1.0f / sum;
#pragma unroll
        for (int t = 0; t < 5; ++t) pr[t][r] *= rs;
    }
    _Float16* myP = P_lds[wv];
    {
        f16x4 z = {};
        *(f16x4*)&myP[lr * 104 + 80 + quad * 4] = z;
    }
#pragma unroll
    for (int t = 0; t < 5; ++t)
#pragma unroll
        for (int r = 0; r < 4; ++r)
            myP[(quad * 4 + r) * 104 + t * 16 + lr] = (_Float16)pr[t][r];
    __syncthreads();

    f32x4 oacc[4] = {};
#pragma unroll
    for (int ks = 0; ks < 3; ++ks) {
        f16x8 pf = *(const f16x8*)&myP[lr * 104 + ks * 32 + quad * 8];
#pragma unroll
        for (int t = 0; t < 4; ++t) {
            f16x8 vf = *(const f16x8*)&Vt_lds[(t * 16 + lr) * 104 + ks * 32 + quad * 8];
            oacc[t] = __builtin_amdgcn_mfma_f32_16x16x32_f16(pf, vf, oacc[t], 0, 0, 0);
        }
    }
#pragma unroll
    for (int t = 0; t < 4; ++t)
#pragma unroll
        for (int r = 0; r < 4; ++r)
            attn_out[(size_t)(s0 + quad * 4 + r) * HIDDEN + h * 64 + t * 16 + lr] = (_Float16)oacc[t][r];
}

// ---------------- launch ----------------
extern "C" void kernel_launch(void* const* d_in, const int* in_sizes, int n_in,
                              void* d_out, int out_size, void* d_ws, size_t ws_size,
                              hipStream_t stream) {
    const float* hs      = (const float*)d_in[0];
    const int*   mask    = (const int*)  d_in[1];
    const int*   pos_ids = (const int*)  d_in[2];
    const float* wq      = (const float*)d_in[3];
    const float* wk      = (const float*)d_in[4];
    const float* wvv     = (const float*)d_in[5];
    const float* wo      = (const float*)d_in[6];
    float* out = (float*)d_out;

    char* ws = (char*)d_ws;
    _Float16* wqkvT   = (_Float16*)(ws + 0);                    // 1536x1024 f16 (3 MB)
    _Float16* woT     = (_Float16*)(ws + (3u << 20));           // 1024x1024 f16 (2 MB)
    _Float16* hsf16   = (_Float16*)(ws + (5u << 20));           // 2048x1024 f16 (4 MB)
    _Float16* qkvf16  = (_Float16*)(ws + (9u << 20));           // 2048x1536 f16 (6 MB)
    _Float16* attnf16 = (_Float16*)(ws + (15u << 20));          // 2048x1024 f16 (4 MB)
    _Float16* vTs     = (_Float16*)(ws + (19u << 20));          // 256x2128  f16 (~1.1 MB)
    float2*   ropeTab = (float2*)  (ws + (21u << 20));          // 2048x32 float2 (512 KB)

    // 1. prep: transposes (2560, q/k rope-permuted) + convert (2048) + rope (256) + halo (256)
    prep_kernel<<<5120, 256, 0, stream>>>(hs, hsf16, wq, wk, wvv, wo, wqkvT, woT,
                                          pos_ids, ropeTab, vTs);
    // 2. QKV projection (768 blocks = 3/CU, 4-wave, BK=128) with fused rope / v-transpose
    gemm_qkv<<<768, 256, 0, stream>>>(hsf16, wqkvT, qkvf16, vTs, ropeTab);
    // 3. attention
    attn_mfma<<<dim3(S / 16, NKV), 256, 0, stream>>>(qkvf16, vTs, mask, attnf16);
    // 4. output projection (512 blocks = 2/CU, 4-wave, BK=128) -> f32 out
    gemm_o<<<512, 256, 0, stream>>>(attnf16, woT, out);
}